// Round 21
// baseline (3935.269 us; speedup 1.0000x reference)
//
#include <hip/hip_runtime.h>

typedef __attribute__((ext_vector_type(8))) short bhalf8;
typedef __attribute__((ext_vector_type(4))) float floatx4;

// d_out is FLOAT32 (reference returns f32). Harness compares bf16(top-16-bits).
// 20-round lesson: we were writing u16 bf16 into this f32 buffer.

// ---- device-global scratch ----
__device__ unsigned short g_whh[3072*768];     // bf16 W_hh
__device__ unsigned short g_wih[3072*768];     // bf16 W_ih
__device__ unsigned short g_wcln[1536*768];    // bf16 [Ww;Wb]
__device__ unsigned short g_whl[128*768];      // bf16 [Wh;Wt;pad]
__device__ unsigned short g_h2[2*64*768];      // bf16 h ping-pong (MFMA)
__device__ float g_cbuf[64*768];               // f32 c (MFMA)
__device__ float g_xg[1024*3072];              // f32 xgates (MFMA)
__device__ float g_wv[64*768], g_bv[64*768];
__device__ float g_bias[3072];                 // b_ih + b_hh
__device__ float g_cw[768], g_cb[768];
__device__ float g_bh[64], g_bt[64];
// scalar arbiter
__device__ float g_xg2[1024*3072];
__device__ float g_h2f[2*64*768];
__device__ float g_c2f[64*768];
__device__ float g_wv2[64*768], g_bv2[64*768];

static __device__ __forceinline__ unsigned short f2bf(float f){
  unsigned u = __builtin_bit_cast(unsigned, f);
  u = (u + 0x7FFFu + ((u >> 16) & 1u)) >> 16;
  return (unsigned short)u;
}
static __device__ __forceinline__ float sigm(float x){ return 1.0f/(1.0f + __expf(-x)); }
static __device__ __forceinline__ float tanhq(float x){ float e = __expf(-2.0f*x); return (1.0f - e)/(1.0f + e); }

// ---------------- K0: weight conversions + state zero-init ----------------
__global__ __launch_bounds__(256) void casrel_prep(
    const float* __restrict__ W_ih, const float* __restrict__ W_hh,
    const float* __restrict__ Ww,   const float* __restrict__ Wb,
    const float* __restrict__ Wh,   const float* __restrict__ Wt,
    const float* __restrict__ b_ih, const float* __restrict__ b_hh,
    const float* __restrict__ cw,   const float* __restrict__ cb,
    const float* __restrict__ bh,   const float* __restrict__ bt){
  const long NW = 2359296, NC = 1179648, NL = 98304;
  const long NH = 98304, NCF = 49152, NB = 3072, NV = 768, NR = 64, NZF = 147456;
  const long total = NW*2 + NC + NL + NH + NCF + NB + NV*2 + NR*2 + NZF;
  for(long i = (long)blockIdx.x*256 + threadIdx.x; i < total; i += (long)gridDim.x*256){
    long j = i;
    if(j < NW){ g_whh[j] = f2bf(W_hh[j]); continue; } j -= NW;
    if(j < NW){ g_wih[j] = f2bf(W_ih[j]); continue; } j -= NW;
    if(j < NC){ g_wcln[j] = (j < 589824) ? f2bf(Ww[j]) : f2bf(Wb[j - 589824]); continue; } j -= NC;
    if(j < NL){ long r = j / 768, k = j - r*768;
                float v = 0.0f;
                if(r < 51) v = Wh[r*768 + k]; else if(r < 102) v = Wt[(r-51)*768 + k];
                g_whl[j] = f2bf(v); continue; } j -= NL;
    if(j < NH){ g_h2[j] = 0; continue; } j -= NH;
    if(j < NCF){ g_cbuf[j] = 0.0f; continue; } j -= NCF;
    if(j < NB){ g_bias[j] = b_ih[j] + b_hh[j]; continue; } j -= NB;
    if(j < NV){ g_cw[j] = cw[j]; continue; } j -= NV;
    if(j < NV){ g_cb[j] = cb[j]; continue; } j -= NV;
    if(j < NR){ g_bh[j] = (j < 51) ? bh[j] : 0.0f; continue; } j -= NR;
    if(j < NR){ g_bt[j] = (j < 51) ? bt[j] : 0.0f; continue; } j -= NR;
    if(j < 98304){ g_h2f[j] = 0.0f; continue; } j -= 98304;
    g_c2f[j] = 0.0f;
  }
}

// ================= SCALAR ARBITER (f32) -> heads (Output 0) =================

__global__ __launch_bounds__(256) void s_xgates(
    const float* __restrict__ embed, const int* __restrict__ head,
    const float* __restrict__ W_ih){
  __shared__ float xs[768];
  const int m = blockIdx.x, b = m >> 4, t = m & 15;
  int pos = head[b] + t; pos = pos < 0 ? 0 : (pos > 511 ? 511 : pos);
  const float* xrow = embed + ((long)b*512 + pos)*768;
  for(int i = threadIdx.x; i < 768; i += 256) xs[i] = xrow[i];
  __syncthreads();
  const int n = blockIdx.y*256 + threadIdx.x;
  const float* wrow = W_ih + (long)n*768;
  float acc = g_bias[n];
  for(int k = 0; k < 768; ++k) acc += xs[k] * wrow[k];
  g_xg2[(long)m*3072 + n] = acc;
}

__global__ __launch_bounds__(256) void s_step(
    const float* __restrict__ W_hh,
    const int* __restrict__ head, const int* __restrict__ tail, int t){
  __shared__ float hs[768];
  const float* hin = g_h2f + (t & 1)*49152;
  float* hout = g_h2f + ((t & 1) ^ 1)*49152;
  const int b = blockIdx.x;
  for(int i = threadIdx.x; i < 768; i += 256) hs[i] = hin[b*768 + i];
  __syncthreads();
  const int j = blockIdx.y*256 + threadIdx.x;
  const float* xp = g_xg2 + ((long)(b*16 + t))*3072 + j;
  float Gi = xp[0], Gf = xp[768], Gg = xp[1536], Go = xp[2304];
  const float* wi = W_hh + (long)j*768;
  const float* wf = W_hh + (long)(768 + j)*768;
  const float* wg = W_hh + (long)(1536 + j)*768;
  const float* wo = W_hh + (long)(2304 + j)*768;
  for(int k = 0; k < 768; ++k){
    float h = hs[k];
    Gi += h*wi[k]; Gf += h*wf[k]; Gg += h*wg[k]; Go += h*wo[k];
  }
  const int cell = b*768 + j;
  if(t <= tail[b] - head[b]){
    float c = g_c2f[cell];
    c = sigm(Gf)*c + sigm(Gi)*tanhq(Gg);
    g_c2f[cell] = c;
    hout[cell] = sigm(Go)*tanhq(c);
  } else {
    hout[cell] = hs[j];
  }
}

__global__ __launch_bounds__(256) void s_clnproj(
    const float* __restrict__ Ww, const float* __restrict__ Wb){
  __shared__ float hs[768];
  const int b = blockIdx.x;
  for(int i = threadIdx.x; i < 768; i += 256) hs[i] = g_h2f[b*768 + i];
  __syncthreads();
  const int j = blockIdx.y*256 + threadIdx.x;          // [0,1536)
  const float* wrow = (j < 768) ? (Ww + (long)j*768) : (Wb + (long)(j-768)*768);
  float acc = 0.f;
  for(int k = 0; k < 768; ++k) acc += hs[k] * wrow[k];
  if(j < 768) g_wv2[b*768 + j] = acc + g_cw[j];
  else        g_bv2[b*768 + (j-768)] = acc + g_cb[j-768];
}

__global__ __launch_bounds__(256) void s_heads(
    const float* __restrict__ embed, const float* __restrict__ Wh,
    float* __restrict__ out){
  __shared__ float ns[768];
  __shared__ float rsum[256], rsq[256];
  const int s = blockIdx.x, b = blockIdx.y, tid = threadIdx.x;
  const float* xrow = embed + ((long)b*512 + s)*768;
  float sm = 0.f, sq = 0.f;
  for(int i = tid; i < 768; i += 256){ float v = xrow[i]; sm += v; sq += v*v; }
  rsum[tid] = sm; rsq[tid] = sq;
  __syncthreads();
  for(int o = 128; o > 0; o >>= 1){
    if(tid < o){ rsum[tid] += rsum[tid+o]; rsq[tid] += rsq[tid+o]; }
    __syncthreads();
  }
  const float mu = rsum[0] * (1.0f/768.0f);
  const float var = rsq[0] * (1.0f/768.0f) - mu*mu;
  const float rs = 1.0f/(sqrtf(var + 1e-12f) + 1e-12f);
  for(int i = tid; i < 768; i += 256)
    ns[i] = (xrow[i] - mu)*rs*g_wv2[b*768 + i] + g_bv2[b*768 + i];
  __syncthreads();
  if(tid < 51){
    const float* wrow = Wh + (long)tid*768;
    float acc = g_bh[tid];
    for(int k = 0; k < 768; ++k) acc += ns[k]*wrow[k];
    out[((long)b*512 + s)*51 + tid] = sigm(acc);     // f32 store
  }
}

// ================= MFMA PATH -> tails (Output 1) =================

__global__ __launch_bounds__(256) void casrel_xgates(
    const float* __restrict__ embed, const int* __restrict__ head){
  __shared__ char sB[128*128];
  const int tid = threadIdx.x, l = tid & 63, w = tid >> 6;
  const int n0 = blockIdx.x * 128;
  const int m0 = blockIdx.y * 64 + w*16;
  const int mrow = m0 + (l & 15);
  const int b = mrow >> 4, t = mrow & 15;
  int pos = head[b] + t; pos = pos < 0 ? 0 : (pos > 511 ? 511 : pos);
  const float* aptr = embed + ((long)b*512 + pos)*768 + ((l >> 4)*8);
  floatx4 acc[8];
  #pragma unroll
  for(int q=0;q<8;q++){ acc[q][0]=0.f; acc[q][1]=0.f; acc[q][2]=0.f; acc[q][3]=0.f; }
  for(int kt=0; kt<12; ++kt){
    __syncthreads();
    #pragma unroll
    for(int j=0;j<4;j++){
      int f = tid + 256*j;
      int row = f >> 3, seg = f & 7;
      uint4 v = *(const uint4*)(g_wih + ((long)(n0+row))*768 + kt*64 + seg*8);
      *(uint4*)(sB + row*128 + ((seg*16) ^ ((row & 7) << 4))) = v;
    }
    __syncthreads();
    #pragma unroll
    for(int ks=0; ks<2; ++ks){
      const int k = kt*64 + ks*32;
      float4 lo = *(const float4*)(aptr + k);
      float4 hi = *(const float4*)(aptr + k + 4);
      bhalf8 a;
      a[0]=(short)f2bf(lo.x); a[1]=(short)f2bf(lo.y); a[2]=(short)f2bf(lo.z); a[3]=(short)f2bf(lo.w);
      a[4]=(short)f2bf(hi.x); a[5]=(short)f2bf(hi.y); a[6]=(short)f2bf(hi.z); a[7]=(short)f2bf(hi.w);
      const int kb = ks*64 + ((l >> 4)*16);
      #pragma unroll
      for(int q=0;q<8;q++){
        int row = q*16 + (l & 15);
        bhalf8 bb = *(const bhalf8*)(sB + row*128 + (kb ^ ((row & 7) << 4)));
        acc[q] = __builtin_amdgcn_mfma_f32_16x16x32_bf16(a, bb, acc[q], 0, 0, 0);
      }
    }
  }
  #pragma unroll
  for(int q=0;q<8;q++){
    const int n = n0 + q*16 + (l & 15);
    const float bias = g_bias[n];
    #pragma unroll
    for(int r=0;r<4;r++){
      const int m = m0 + (l >> 4)*4 + r;
      g_xg[(long)m*3072 + n] = acc[q][r] + bias;
    }
  }
}

__global__ __launch_bounds__(256) void casrel_step(
    const int* __restrict__ head, const int* __restrict__ tail, int t){
  __shared__ char sW[64*768];
  const unsigned short* hin = g_h2 + (t & 1)*49152;
  unsigned short* hout = g_h2 + ((t & 1) ^ 1)*49152;
  const int tid = threadIdx.x, l = tid & 63, w = tid >> 6;
  const int j0 = blockIdx.x * 16;
  const int jown = j0 + (l & 15);
  const int arow = w*16 + (l & 15);
  floatx4 acc[4];
  #pragma unroll
  for(int g=0;g<4;g++){ acc[g][0]=0.f; acc[g][1]=0.f; acc[g][2]=0.f; acc[g][3]=0.f; }
  for(int kt=0; kt<2; ++kt){
    __syncthreads();
    #pragma unroll
    for(int j=0;j<12;j++){
      int f = tid + 256*j;
      int row = f / 48, seg = f - row*48;
      int grow = (row >> 4)*768 + j0 + (row & 15);
      uint4 v = *(const uint4*)(g_whh + (long)grow*768 + kt*384 + seg*8);
      *(uint4*)(sW + row*768 + ((seg*16) ^ ((row & 7) << 4))) = v;
    }
    __syncthreads();
    const unsigned short* ap = hin + arow*768 + kt*384 + ((l >> 4)*8);
    #pragma unroll 4
    for(int ks=0; ks<12; ++ks){
      bhalf8 a = *(const bhalf8*)(ap + ks*32);
      const int kb = ks*64 + ((l >> 4)*16);
      #pragma unroll
      for(int g=0;g<4;g++){
        int row = g*16 + (l & 15);
        bhalf8 bb = *(const bhalf8*)(sW + row*768 + (kb ^ ((row & 7) << 4)));
        acc[g] = __builtin_amdgcn_mfma_f32_16x16x32_bf16(a, bb, acc[g], 0, 0, 0);
      }
    }
  }
  #pragma unroll
  for(int r=0;r<4;r++){
    const int b = w*16 + (l >> 4)*4 + r;
    const int cell = b*768 + jown;
    const float* xp = g_xg + ((long)(b*16 + t))*3072 + jown;
    float Gi = acc[0][r] + xp[0];
    float Gf = acc[1][r] + xp[768];
    float Gg = acc[2][r] + xp[1536];
    float Go = acc[3][r] + xp[2304];
    if(t <= tail[b] - head[b]){
      float c = g_cbuf[cell];
      float ig = sigm(Gi), fg = sigm(Gf), gg = tanhq(Gg), og = sigm(Go);
      c = fg*c + ig*gg;
      g_cbuf[cell] = c;
      hout[cell] = f2bf(og*tanhq(c));
    } else {
      hout[cell] = hin[cell];
    }
  }
}

__global__ __launch_bounds__(256) void casrel_clnproj(){
  __shared__ char sW[32*1536];
  const int tid = threadIdx.x, l = tid & 63, w = tid >> 6;
  const int n0c = blockIdx.x * 32;
  #pragma unroll
  for(int j=0;j<12;j++){
    int f = tid + 256*j;
    int row = f / 96, seg = f - row*96;
    uint4 v = *(const uint4*)(g_wcln + (long)(n0c+row)*768 + seg*8);
    *(uint4*)(sW + row*1536 + ((seg*16) ^ ((row & 7) << 4))) = v;
  }
  __syncthreads();
  const int arow = w*16 + (l & 15);
  floatx4 acc2[2];
  #pragma unroll
  for(int q=0;q<2;q++){ acc2[q][0]=0.f; acc2[q][1]=0.f; acc2[q][2]=0.f; acc2[q][3]=0.f; }
  const unsigned short* ap2 = g_h2 + arow*768 + ((l >> 4)*8);
  for(int ks=0; ks<24; ++ks){
    bhalf8 a = *(const bhalf8*)(ap2 + ks*32);
    const int kb = ks*64 + ((l >> 4)*16);
    #pragma unroll
    for(int q=0;q<2;q++){
      int row = q*16 + (l & 15);
      bhalf8 bb = *(const bhalf8*)(sW + row*1536 + (kb ^ ((row & 7) << 4)));
      acc2[q] = __builtin_amdgcn_mfma_f32_16x16x32_bf16(a, bb, acc2[q], 0, 0, 0);
    }
  }
  #pragma unroll
  for(int q=0;q<2;q++){
    const int n = n0c + q*16 + (l & 15);
    #pragma unroll
    for(int r=0;r<4;r++){
      const int b = w*16 + (l >> 4)*4 + r;
      float v = acc2[q][r];
      if(n < 768) g_wv[b*768 + n] = v + g_cw[n];
      else        g_bv[b*768 + (n - 768)] = v + g_cb[n - 768];
    }
  }
}

__global__ __launch_bounds__(256) void casrel_out(
    const float* __restrict__ embed, float* __restrict__ out){
  __shared__ char sB[128*128];
  __shared__ char sE[32*128];
  __shared__ float sMu[32], sRs[32];
  const int tid = threadIdx.x, l = tid & 63, w = tid >> 6;
  const int b = blockIdx.y;
  const int s0 = blockIdx.x * 32;
  const float* xbase = embed + ((long)b*512 + s0)*768;
  for(int rr=0; rr<8; ++rr){
    const int row = w*8 + rr;
    const float* rp = xbase + row*768;
    float sm = 0.f, sq = 0.f;
    #pragma unroll
    for(int q=0;q<3;q++){
      float4 v = *(const float4*)(rp + l*4 + q*256);
      sm += v.x + v.y + v.z + v.w;
      sq += v.x*v.x + v.y*v.y + v.z*v.z + v.w*v.w;
    }
    #pragma unroll
    for(int o=32;o>0;o>>=1){ sm += __shfl_xor(sm, o); sq += __shfl_xor(sq, o); }
    if(l == 0){
      float mu = sm * (1.0f/768.0f);
      float var = sq * (1.0f/768.0f) - mu*mu;
      sMu[row] = mu;
      sRs[row] = 1.0f/(sqrtf(var + 1e-12f) + 1e-12f);
    }
  }
  __syncthreads();
  const int mf = w >> 1, nb = (w & 1)*4;
  floatx4 acc[4];
  #pragma unroll
  for(int q=0;q<4;q++){ acc[q][0]=0.f; acc[q][1]=0.f; acc[q][2]=0.f; acc[q][3]=0.f; }
  for(int kt=0; kt<12; ++kt){
    __syncthreads();
    #pragma unroll
    for(int j=0;j<4;j++){
      int f = tid + 256*j;
      int row = f >> 3, seg = f & 7;
      uint4 v = *(const uint4*)(g_whl + (long)row*768 + kt*64 + seg*8);
      *(uint4*)(sB + row*128 + ((seg*16) ^ ((row & 7) << 4))) = v;
    }
    #pragma unroll
    for(int j=0;j<2;j++){
      int f = tid + 256*j;
      int row = f >> 4, cs = f & 15;
      int k = kt*64 + cs*4;
      float4 x4 = *(const float4*)(xbase + row*768 + k);
      float4 w4 = *(const float4*)(g_wv + b*768 + k);
      float4 c4 = *(const float4*)(g_bv + b*768 + k);
      float mu = sMu[row], rs = sRs[row];
      unsigned long long pk =
          (unsigned long long)f2bf((x4.x - mu)*rs*w4.x + c4.x)
        | ((unsigned long long)f2bf((x4.y - mu)*rs*w4.y + c4.y) << 16)
        | ((unsigned long long)f2bf((x4.z - mu)*rs*w4.z + c4.z) << 32)
        | ((unsigned long long)f2bf((x4.w - mu)*rs*w4.w + c4.w) << 48);
      *(unsigned long long*)(sE + row*128 + ((cs*8) ^ ((row & 7) << 4))) = pk;
    }
    __syncthreads();
    #pragma unroll
    for(int ks=0; ks<2; ++ks){
      const int arow = mf*16 + (l & 15);
      const int kb = ks*64 + ((l >> 4)*16);
      bhalf8 a = *(const bhalf8*)(sE + arow*128 + (kb ^ ((arow & 7) << 4)));
      #pragma unroll
      for(int q=0;q<4;q++){
        int row = (nb + q)*16 + (l & 15);
        bhalf8 bb = *(const bhalf8*)(sB + row*128 + (kb ^ ((row & 7) << 4)));
        acc[q] = __builtin_amdgcn_mfma_f32_16x16x32_bf16(a, bb, acc[q], 0, 0, 0);
      }
    }
  }
  const long HT = (long)64*512*51;
  #pragma unroll
  for(int q=0;q<4;q++){
    const int n = (nb + q)*16 + (l & 15);
    if(n < 51 || n >= 102) continue;                 // TAILS ONLY (heads = scalar arbiter)
    const int rr = n - 51;
    const float bias = g_bt[rr];
    #pragma unroll
    for(int r=0;r<4;r++){
      const int s = s0 + mf*16 + (l >> 4)*4 + r;
      out[HT + ((long)b*512 + s)*51 + rr] = sigm(acc[q][r] + bias);   // f32 store
    }
  }
}

extern "C" void kernel_launch(void* const* d_in, const int* in_sizes, int n_in,
                              void* d_out, int out_size, void* d_ws, size_t ws_size,
                              hipStream_t stream){
  const float* embed = (const float*)d_in[0];
  const int*   head  = (const int*)d_in[1];
  const int*   tail  = (const int*)d_in[2];
  const float* W_ih  = (const float*)d_in[3];
  const float* W_hh  = (const float*)d_in[4];
  const float* b_ih  = (const float*)d_in[5];
  const float* b_hh  = (const float*)d_in[6];
  const float* cw    = (const float*)d_in[7];
  const float* cb    = (const float*)d_in[8];
  const float* Ww    = (const float*)d_in[9];
  const float* Wb    = (const float*)d_in[10];
  const float* Wh    = (const float*)d_in[11];
  const float* bh    = (const float*)d_in[12];
  const float* Wt    = (const float*)d_in[13];
  const float* bt    = (const float*)d_in[14];
  float* out = (float*)d_out;
  (void)d_ws; (void)ws_size;

  casrel_prep<<<dim3(4096), dim3(256), 0, stream>>>(W_ih, W_hh, Ww, Wb, Wh, Wt,
                                                    b_ih, b_hh, cw, cb, bh, bt);

  // scalar arbiter -> heads (Output 0)
  s_xgates<<<dim3(1024,12), dim3(256), 0, stream>>>(embed, head, W_ih);
  for(int t=0; t<16; ++t)
    s_step<<<dim3(64,3), dim3(256), 0, stream>>>(W_hh, head, tail, t);
  s_clnproj<<<dim3(64,6), dim3(256), 0, stream>>>(Ww, Wb);
  s_heads<<<dim3(512,64), dim3(256), 0, stream>>>(embed, Wh, out);

  // MFMA path -> tails (Output 1)
  casrel_xgates<<<dim3(24,16), dim3(256), 0, stream>>>(embed, head);
  for(int t=0; t<16; ++t)
    casrel_step<<<dim3(48), dim3(256), 0, stream>>>(head, tail, t);
  casrel_clnproj<<<dim3(48), dim3(256), 0, stream>>>();
  casrel_out<<<dim3(16,64), dim3(256), 0, stream>>>(embed, out);
}

// Round 22
// 282.234 us; speedup vs baseline: 13.9433x; 13.9433x over previous
//
#include <hip/hip_runtime.h>

typedef __attribute__((ext_vector_type(8))) short bhalf8;
typedef __attribute__((ext_vector_type(4))) float floatx4;

// d_out is FLOAT32. Full MFMA pipeline -> both outputs.

// ---- device-global scratch ----
__device__ unsigned short g_whh[3072*768];     // bf16 W_hh
__device__ unsigned short g_wih[3072*768];     // bf16 W_ih
__device__ unsigned short g_wcln[1536*768];    // bf16 [Ww;Wb]
__device__ unsigned short g_whl[128*768];      // bf16 [Wh;Wt;pad]
__device__ unsigned short g_h2[2*64*768];      // bf16 h ping-pong
__device__ float g_cbuf[64*768];               // f32 c
__device__ float g_xg[1024*3072];              // f32 xgates
__device__ float g_wv[64*768], g_bv[64*768];   // f32 CLN w,b
__device__ float g_bias[3072];                 // b_ih + b_hh
__device__ float g_cw[768], g_cb[768];
__device__ float g_bh[64], g_bt[64];

static __device__ __forceinline__ unsigned short f2bf(float f){
  unsigned u = __builtin_bit_cast(unsigned, f);
  u = (u + 0x7FFFu + ((u >> 16) & 1u)) >> 16;
  return (unsigned short)u;
}
static __device__ __forceinline__ float sigm(float x){ return 1.0f/(1.0f + __expf(-x)); }
static __device__ __forceinline__ float tanhq(float x){ float e = __expf(-2.0f*x); return (1.0f - e)/(1.0f + e); }

// ---------------- K0: weight conversions + state zero-init ----------------
__global__ __launch_bounds__(256) void casrel_prep(
    const float* __restrict__ W_ih, const float* __restrict__ W_hh,
    const float* __restrict__ Ww,   const float* __restrict__ Wb,
    const float* __restrict__ Wh,   const float* __restrict__ Wt,
    const float* __restrict__ b_ih, const float* __restrict__ b_hh,
    const float* __restrict__ cw,   const float* __restrict__ cb,
    const float* __restrict__ bh,   const float* __restrict__ bt){
  const long NW = 2359296, NC = 1179648, NL = 98304;
  const long NH = 98304, NCF = 49152, NB = 3072, NV = 768, NR = 64;
  const long total = NW*2 + NC + NL + NH + NCF + NB + NV*2 + NR*2;
  for(long i = (long)blockIdx.x*256 + threadIdx.x; i < total; i += (long)gridDim.x*256){
    long j = i;
    if(j < NW){ g_whh[j] = f2bf(W_hh[j]); continue; } j -= NW;
    if(j < NW){ g_wih[j] = f2bf(W_ih[j]); continue; } j -= NW;
    if(j < NC){ g_wcln[j] = (j < 589824) ? f2bf(Ww[j]) : f2bf(Wb[j - 589824]); continue; } j -= NC;
    if(j < NL){ long r = j / 768, k = j - r*768;
                float v = 0.0f;
                if(r < 51) v = Wh[r*768 + k]; else if(r < 102) v = Wt[(r-51)*768 + k];
                g_whl[j] = f2bf(v); continue; } j -= NL;
    if(j < NH){ g_h2[j] = 0; continue; } j -= NH;
    if(j < NCF){ g_cbuf[j] = 0.0f; continue; } j -= NCF;
    if(j < NB){ g_bias[j] = b_ih[j] + b_hh[j]; continue; } j -= NB;
    if(j < NV){ g_cw[j] = cw[j]; continue; } j -= NV;
    if(j < NV){ g_cb[j] = cb[j]; continue; } j -= NV;
    if(j < NR){ g_bh[j] = (j < 51) ? bh[j] : 0.0f; continue; } j -= NR;
    g_bt[j] = (j < 51) ? bt[j] : 0.0f;
  }
}

// ---------------- K1: xgates = gather(embed) @ W_ih^T + (b_ih + b_hh) ----------------
__global__ __launch_bounds__(256) void casrel_xgates(
    const float* __restrict__ embed, const int* __restrict__ head){
  __shared__ char sB[128*128];
  const int tid = threadIdx.x, l = tid & 63, w = tid >> 6;
  const int n0 = blockIdx.x * 128;
  const int m0 = blockIdx.y * 64 + w*16;
  const int mrow = m0 + (l & 15);
  const int b = mrow >> 4, t = mrow & 15;
  int pos = head[b] + t; pos = pos < 0 ? 0 : (pos > 511 ? 511 : pos);
  const float* aptr = embed + ((long)b*512 + pos)*768 + ((l >> 4)*8);
  floatx4 acc[8];
  #pragma unroll
  for(int q=0;q<8;q++){ acc[q][0]=0.f; acc[q][1]=0.f; acc[q][2]=0.f; acc[q][3]=0.f; }
  for(int kt=0; kt<12; ++kt){
    __syncthreads();
    #pragma unroll
    for(int j=0;j<4;j++){
      int f = tid + 256*j;
      int row = f >> 3, seg = f & 7;
      uint4 v = *(const uint4*)(g_wih + ((long)(n0+row))*768 + kt*64 + seg*8);
      *(uint4*)(sB + row*128 + ((seg*16) ^ ((row & 7) << 4))) = v;
    }
    __syncthreads();
    #pragma unroll
    for(int ks=0; ks<2; ++ks){
      const int k = kt*64 + ks*32;
      float4 lo = *(const float4*)(aptr + k);
      float4 hi = *(const float4*)(aptr + k + 4);
      bhalf8 a;
      a[0]=(short)f2bf(lo.x); a[1]=(short)f2bf(lo.y); a[2]=(short)f2bf(lo.z); a[3]=(short)f2bf(lo.w);
      a[4]=(short)f2bf(hi.x); a[5]=(short)f2bf(hi.y); a[6]=(short)f2bf(hi.z); a[7]=(short)f2bf(hi.w);
      const int kb = ks*64 + ((l >> 4)*16);
      #pragma unroll
      for(int q=0;q<8;q++){
        int row = q*16 + (l & 15);
        bhalf8 bb = *(const bhalf8*)(sB + row*128 + (kb ^ ((row & 7) << 4)));
        acc[q] = __builtin_amdgcn_mfma_f32_16x16x32_bf16(a, bb, acc[q], 0, 0, 0);
      }
    }
  }
  #pragma unroll
  for(int q=0;q<8;q++){
    const int n = n0 + q*16 + (l & 15);
    const float bias = g_bias[n];
    #pragma unroll
    for(int r=0;r<4;r++){
      const int m = m0 + (l >> 4)*4 + r;
      g_xg[(long)m*3072 + n] = acc[q][r] + bias;
    }
  }
}

// ---------------- K2a: one LSTM step ----------------
__global__ __launch_bounds__(256) void casrel_step(
    const int* __restrict__ head, const int* __restrict__ tail, int t){
  __shared__ char sW[64*768];
  const unsigned short* hin = g_h2 + (t & 1)*49152;
  unsigned short* hout = g_h2 + ((t & 1) ^ 1)*49152;
  const int tid = threadIdx.x, l = tid & 63, w = tid >> 6;
  const int j0 = blockIdx.x * 16;
  const int jown = j0 + (l & 15);
  const int arow = w*16 + (l & 15);
  floatx4 acc[4];
  #pragma unroll
  for(int g=0;g<4;g++){ acc[g][0]=0.f; acc[g][1]=0.f; acc[g][2]=0.f; acc[g][3]=0.f; }
  for(int kt=0; kt<2; ++kt){
    __syncthreads();
    #pragma unroll
    for(int j=0;j<12;j++){
      int f = tid + 256*j;
      int row = f / 48, seg = f - row*48;
      int grow = (row >> 4)*768 + j0 + (row & 15);
      uint4 v = *(const uint4*)(g_whh + (long)grow*768 + kt*384 + seg*8);
      *(uint4*)(sW + row*768 + ((seg*16) ^ ((row & 7) << 4))) = v;
    }
    __syncthreads();
    const unsigned short* ap = hin + arow*768 + kt*384 + ((l >> 4)*8);
    #pragma unroll 4
    for(int ks=0; ks<12; ++ks){
      bhalf8 a = *(const bhalf8*)(ap + ks*32);
      const int kb = ks*64 + ((l >> 4)*16);
      #pragma unroll
      for(int g=0;g<4;g++){
        int row = g*16 + (l & 15);
        bhalf8 bb = *(const bhalf8*)(sW + row*768 + (kb ^ ((row & 7) << 4)));
        acc[g] = __builtin_amdgcn_mfma_f32_16x16x32_bf16(a, bb, acc[g], 0, 0, 0);
      }
    }
  }
  #pragma unroll
  for(int r=0;r<4;r++){
    const int b = w*16 + (l >> 4)*4 + r;
    const int cell = b*768 + jown;
    const float* xp = g_xg + ((long)(b*16 + t))*3072 + jown;
    float Gi = acc[0][r] + xp[0];
    float Gf = acc[1][r] + xp[768];
    float Gg = acc[2][r] + xp[1536];
    float Go = acc[3][r] + xp[2304];
    if(t <= tail[b] - head[b]){
      float c = g_cbuf[cell];
      float ig = sigm(Gi), fg = sigm(Gf), gg = tanhq(Gg), og = sigm(Go);
      c = fg*c + ig*gg;
      g_cbuf[cell] = c;
      hout[cell] = f2bf(og*tanhq(c));
    } else {
      hout[cell] = hin[cell];
    }
  }
}

// ---------------- K2b: wv = hn@Ww^T + cw ; bv = hn@Wb^T + cb ----------------
__global__ __launch_bounds__(256) void casrel_clnproj(){
  __shared__ char sW[32*1536];
  const int tid = threadIdx.x, l = tid & 63, w = tid >> 6;
  const int n0c = blockIdx.x * 32;
  #pragma unroll
  for(int j=0;j<12;j++){
    int f = tid + 256*j;
    int row = f / 96, seg = f - row*96;
    uint4 v = *(const uint4*)(g_wcln + (long)(n0c+row)*768 + seg*8);
    *(uint4*)(sW + row*1536 + ((seg*16) ^ ((row & 7) << 4))) = v;
  }
  __syncthreads();
  const int arow = w*16 + (l & 15);
  floatx4 acc2[2];
  #pragma unroll
  for(int q=0;q<2;q++){ acc2[q][0]=0.f; acc2[q][1]=0.f; acc2[q][2]=0.f; acc2[q][3]=0.f; }
  const unsigned short* ap2 = g_h2 + arow*768 + ((l >> 4)*8);   // buf 0 = final h
  for(int ks=0; ks<24; ++ks){
    bhalf8 a = *(const bhalf8*)(ap2 + ks*32);
    const int kb = ks*64 + ((l >> 4)*16);
    #pragma unroll
    for(int q=0;q<2;q++){
      int row = q*16 + (l & 15);
      bhalf8 bb = *(const bhalf8*)(sW + row*1536 + (kb ^ ((row & 7) << 4)));
      acc2[q] = __builtin_amdgcn_mfma_f32_16x16x32_bf16(a, bb, acc2[q], 0, 0, 0);
    }
  }
  #pragma unroll
  for(int q=0;q<2;q++){
    const int n = n0c + q*16 + (l & 15);
    #pragma unroll
    for(int r=0;r<4;r++){
      const int b = w*16 + (l >> 4)*4 + r;
      float v = acc2[q][r];
      if(n < 768) g_wv[b*768 + n] = v + g_cw[n];
      else        g_bv[b*768 + (n - 768)] = v + g_cb[n - 768];
    }
  }
}

// ---------------- K3: fused cond-LN + heads + tails + sigmoid -> f32 out ----------------
__global__ __launch_bounds__(256) void casrel_out(
    const float* __restrict__ embed, float* __restrict__ out){
  __shared__ char sB[128*128];
  __shared__ char sE[32*128];
  __shared__ float sMu[32], sRs[32];
  const int tid = threadIdx.x, l = tid & 63, w = tid >> 6;
  const int b = blockIdx.y;
  const int s0 = blockIdx.x * 32;
  const float* xbase = embed + ((long)b*512 + s0)*768;
  for(int rr=0; rr<8; ++rr){
    const int row = w*8 + rr;
    const float* rp = xbase + row*768;
    float sm = 0.f, sq = 0.f;
    #pragma unroll
    for(int q=0;q<3;q++){
      float4 v = *(const float4*)(rp + l*4 + q*256);
      sm += v.x + v.y + v.z + v.w;
      sq += v.x*v.x + v.y*v.y + v.z*v.z + v.w*v.w;
    }
    #pragma unroll
    for(int o=32;o>0;o>>=1){ sm += __shfl_xor(sm, o); sq += __shfl_xor(sq, o); }
    if(l == 0){
      float mu = sm * (1.0f/768.0f);
      float var = sq * (1.0f/768.0f) - mu*mu;
      sMu[row] = mu;
      sRs[row] = 1.0f/(sqrtf(var + 1e-12f) + 1e-12f);
    }
  }
  __syncthreads();
  const int mf = w >> 1, nb = (w & 1)*4;
  floatx4 acc[4];
  #pragma unroll
  for(int q=0;q<4;q++){ acc[q][0]=0.f; acc[q][1]=0.f; acc[q][2]=0.f; acc[q][3]=0.f; }
  for(int kt=0; kt<12; ++kt){
    __syncthreads();
    #pragma unroll
    for(int j=0;j<4;j++){
      int f = tid + 256*j;
      int row = f >> 3, seg = f & 7;
      uint4 v = *(const uint4*)(g_whl + (long)row*768 + kt*64 + seg*8);
      *(uint4*)(sB + row*128 + ((seg*16) ^ ((row & 7) << 4))) = v;
    }
    #pragma unroll
    for(int j=0;j<2;j++){
      int f = tid + 256*j;
      int row = f >> 4, cs = f & 15;
      int k = kt*64 + cs*4;
      float4 x4 = *(const float4*)(xbase + row*768 + k);
      float4 w4 = *(const float4*)(g_wv + b*768 + k);
      float4 c4 = *(const float4*)(g_bv + b*768 + k);
      float mu = sMu[row], rs = sRs[row];
      unsigned long long pk =
          (unsigned long long)f2bf((x4.x - mu)*rs*w4.x + c4.x)
        | ((unsigned long long)f2bf((x4.y - mu)*rs*w4.y + c4.y) << 16)
        | ((unsigned long long)f2bf((x4.z - mu)*rs*w4.z + c4.z) << 32)
        | ((unsigned long long)f2bf((x4.w - mu)*rs*w4.w + c4.w) << 48);
      *(unsigned long long*)(sE + row*128 + ((cs*8) ^ ((row & 7) << 4))) = pk;
    }
    __syncthreads();
    #pragma unroll
    for(int ks=0; ks<2; ++ks){
      const int arow = mf*16 + (l & 15);
      const int kb = ks*64 + ((l >> 4)*16);
      bhalf8 a = *(const bhalf8*)(sE + arow*128 + (kb ^ ((arow & 7) << 4)));
      #pragma unroll
      for(int q=0;q<4;q++){
        int row = (nb + q)*16 + (l & 15);
        bhalf8 bb = *(const bhalf8*)(sB + row*128 + (kb ^ ((row & 7) << 4)));
        acc[q] = __builtin_amdgcn_mfma_f32_16x16x32_bf16(a, bb, acc[q], 0, 0, 0);
      }
    }
  }
  const long HT = (long)64*512*51;
  #pragma unroll
  for(int q=0;q<4;q++){
    const int n = (nb + q)*16 + (l & 15);
    if(n >= 102) continue;
    const int rr = (n < 51) ? n : (n - 51);
    const long obase = (n < 51) ? 0 : HT;
    const float bias = (n < 51) ? g_bh[n] : g_bt[n - 51];
    #pragma unroll
    for(int r=0;r<4;r++){
      const int s = s0 + mf*16 + (l >> 4)*4 + r;
      out[obase + ((long)b*512 + s)*51 + rr] = sigm(acc[q][r] + bias);
    }
  }
}

extern "C" void kernel_launch(void* const* d_in, const int* in_sizes, int n_in,
                              void* d_out, int out_size, void* d_ws, size_t ws_size,
                              hipStream_t stream){
  const float* embed = (const float*)d_in[0];
  const int*   head  = (const int*)d_in[1];
  const int*   tail  = (const int*)d_in[2];
  const float* W_ih  = (const float*)d_in[3];
  const float* W_hh  = (const float*)d_in[4];
  const float* b_ih  = (const float*)d_in[5];
  const float* b_hh  = (const float*)d_in[6];
  const float* cw    = (const float*)d_in[7];
  const float* cb    = (const float*)d_in[8];
  const float* Ww    = (const float*)d_in[9];
  const float* Wb    = (const float*)d_in[10];
  const float* Wh    = (const float*)d_in[11];
  const float* bh    = (const float*)d_in[12];
  const float* Wt    = (const float*)d_in[13];
  const float* bt    = (const float*)d_in[14];
  float* out = (float*)d_out;
  (void)d_ws; (void)ws_size;

  casrel_prep<<<dim3(4096), dim3(256), 0, stream>>>(W_ih, W_hh, Ww, Wb, Wh, Wt,
                                                    b_ih, b_hh, cw, cb, bh, bt);
  casrel_xgates<<<dim3(24,16), dim3(256), 0, stream>>>(embed, head);
  for(int t=0; t<16; ++t)
    casrel_step<<<dim3(48), dim3(256), 0, stream>>>(head, tail, t);
  casrel_clnproj<<<dim3(48), dim3(256), 0, stream>>>();
  casrel_out<<<dim3(16,64), dim3(256), 0, stream>>>(embed, out);
}